// Round 1
// 298.765 us; speedup vs baseline: 1.0613x; 1.0613x over previous
//
#include <hip/hip_runtime.h>

typedef unsigned short ushort_t;
typedef short short8 __attribute__((ext_vector_type(8)));
typedef float f32x4 __attribute__((ext_vector_type(4)));
typedef ushort_t ushort8v __attribute__((ext_vector_type(8)));
typedef ushort_t ushort4v __attribute__((ext_vector_type(4)));

#define HWsz 16384
#define NHWsz 65536
// padded LDS row strides (ushorts): stride%128B != 0 -> 2-way max (free)
#define YS 136
#define HS 520

__device__ __forceinline__ float b2f(ushort_t u){ return __uint_as_float(((unsigned)u)<<16); }
__device__ __forceinline__ ushort_t f2b(float f){
  unsigned x = __float_as_uint(f);
  x += 0x7fffu + ((x>>16)&1u);
  return (ushort_t)(x>>16);
}
// tanh-form GELU: max |err| vs exact ~3e-4, below bf16 ulp at |x|~1+.
// gelu = x * e/(1+e), e = exp(2*0.79788456*(x+0.044715 x^3)).
// Written as x - x*rcp(1+e): NaN-free at both infinities.
__device__ __forceinline__ float gelu_fast(float x){
  float t = x*x;
  float e = __expf(x*(1.5957691216f + 0.0713548163f*t));
  return x - x*__builtin_amdgcn_rcpf(1.0f + e);
}

// ---------------- kW: weight preprocessing (once per launch) ----------------
__global__ __launch_bounds__(256) void kW_cvt(const float* __restrict__ w1, const float* __restrict__ w2,
    const float* __restrict__ offw, const float* __restrict__ maskw, const float* __restrict__ dww,
    const float* __restrict__ pw, const float* __restrict__ offb, const float* __restrict__ mb,
    ushort_t* __restrict__ w1b, ushort_t* __restrict__ w2b, ushort_t* __restrict__ owmb,
    float* __restrict__ dwwT, ushort_t* __restrict__ pwh, ushort_t* __restrict__ pwl,
    float* __restrict__ obm){
  int i = blockIdx.x*256 + threadIdx.x;   // 65536
  w1b[i] = f2b(w1[i]);
  w2b[i] = f2b(w2[i]);
  if (i < 16384){
    int row = i >> 7, k = i & 127;
    float v = 0.f;
    if (row < 72) v = offw[row*128 + k];
    else if (row < 108) v = maskw[(row-72)*128 + k];
    owmb[i] = f2b(v);
    float pv = pw[i];
    ushort_t hi = f2b(pv);
    pwh[i] = hi;
    pwl[i] = f2b(pv - b2f(hi));
  }
  if (i < 1152){
    int k = i >> 7, c = i & 127;
    dwwT[i] = dww[c*9 + k];
  }
  if (i < 128){
    obm[i] = (i < 72) ? offb[i] : ((i < 108) ? mb[i-72] : 0.f);
  }
}

// ---------------- kA: LN1, NCHW fp32 -> NHWC bf16 ----------------
__global__ __launch_bounds__(256) void kA_ln1(const float* __restrict__ x,
    const float* __restrict__ w, const float* __restrict__ b,
    ushort_t* __restrict__ xcl){
  __shared__ float tile[128*66];
  __shared__ float psum[256], psq[256];
  __shared__ float ms[64], rs[64];
  int t = threadIdx.x;
  int pos0 = blockIdx.x * 64;
  int n = pos0 >> 14, hw0 = pos0 & 16383;
  const float* xb = x + (size_t)n*128*HWsz + hw0;
  for (int i=0;i<32;i++){
    int e = i*256+t;
    int c = e>>6, p = e&63;
    tile[c*66+p] = xb[(size_t)c*HWsz + p];
  }
  __syncthreads();
  {
    int part = t>>6, p = t&63;
    float s=0.f, q=0.f;
    for (int c=part*32; c<part*32+32; c++){ float v = tile[c*66+p]; s+=v; q+=v*v; }
    psum[part*64+p]=s; psq[part*64+p]=q;
  }
  __syncthreads();
  if (t<64){
    float s=psum[t]+psum[64+t]+psum[128+t]+psum[192+t];
    float q=psq[t]+psq[64+t]+psq[128+t]+psq[192+t];
    float m = s*(1.0f/128.0f);
    float v = q*(1.0f/128.0f)-m*m;
    ms[t]=m; rs[t]=rsqrtf(v+1e-6f);
  }
  __syncthreads();
  for (int i=0;i<32;i++){
    int e = i*256+t;
    int p = e>>7, c = e&127;
    float v = (tile[c*66+p]-ms[p])*rs[p]*w[c]+b[c];
    xcl[(size_t)(pos0+p)*128 + c] = f2b(v);
  }
}

// ---------------- kB: depthwise 3x3 + bias + LN + GELU ----------------
__global__ __launch_bounds__(256) void kB_dw(const ushort_t* __restrict__ xcl,
    const float* __restrict__ dwwT, const float* __restrict__ dwb,
    const float* __restrict__ lnw, const float* __restrict__ lnb,
    ushort_t* __restrict__ x1){
  __shared__ float partS[16*17], partQ[16*17];
  __shared__ float ms[16], rs[16];
  int t = threadIdx.x;
  int pos0 = blockIdx.x*16;
  int n = pos0>>14, hw0 = pos0&16383, h = hw0>>7, w0 = hw0&127;
  int pp = t>>4, l = t&15, ch0 = l*8;
  int w = w0 + pp;
  float acc[8];
  {
    float4 b0 = *(const float4*)(dwb + ch0);
    float4 b1 = *(const float4*)(dwb + ch0 + 4);
    acc[0]=b0.x; acc[1]=b0.y; acc[2]=b0.z; acc[3]=b0.w;
    acc[4]=b1.x; acc[5]=b1.y; acc[6]=b1.z; acc[7]=b1.w;
  }
  #pragma unroll
  for (int kh=0; kh<3; kh++){
    int hy = h + kh - 1;
    if ((unsigned)hy < 128u){
      #pragma unroll
      for (int kw=0; kw<3; kw++){
        int wx = w + kw - 1;
        if ((unsigned)wx < 128u){
          ushort8v xv = *(const ushort8v*)(xcl + ((size_t)(n*16384 + hy*128 + wx))*128 + ch0);
          const float* wr = dwwT + (kh*3+kw)*128 + ch0;
          float4 w0v = *(const float4*)(wr);
          float4 w1v = *(const float4*)(wr+4);
          acc[0] += b2f(xv[0])*w0v.x; acc[1] += b2f(xv[1])*w0v.y;
          acc[2] += b2f(xv[2])*w0v.z; acc[3] += b2f(xv[3])*w0v.w;
          acc[4] += b2f(xv[4])*w1v.x; acc[5] += b2f(xv[5])*w1v.y;
          acc[6] += b2f(xv[6])*w1v.z; acc[7] += b2f(xv[7])*w1v.w;
        }
      }
    }
  }
  {
    float s=0.f, q=0.f;
    #pragma unroll
    for (int j=0;j<8;j++){ s+=acc[j]; q+=acc[j]*acc[j]; }
    partS[pp*17+l]=s; partQ[pp*17+l]=q;
  }
  __syncthreads();
  if (t<16){
    float s=0.f, q=0.f;
    for (int i=0;i<16;i++){ s += partS[t*17+i]; q += partQ[t*17+i]; }
    float m = s*(1.0f/128.0f);
    float var = q*(1.0f/128.0f) - m*m;
    ms[t]=m; rs[t]=rsqrtf(var+1e-6f);
  }
  __syncthreads();
  {
    float m = ms[pp], r = rs[pp];
    float4 lw0 = *(const float4*)(lnw + ch0);
    float4 lw1 = *(const float4*)(lnw + ch0 + 4);
    float4 lb0 = *(const float4*)(lnb + ch0);
    float4 lb1 = *(const float4*)(lnb + ch0 + 4);
    float lw[8] = {lw0.x,lw0.y,lw0.z,lw0.w,lw1.x,lw1.y,lw1.z,lw1.w};
    float lb[8] = {lb0.x,lb0.y,lb0.z,lb0.w,lb1.x,lb1.y,lb1.z,lb1.w};
    ushort8v o;
    #pragma unroll
    for (int j=0;j<8;j++){
      float v = (acc[j]-m)*r*lw[j]+lb[j];
      o[j] = f2b(gelu_fast(v));
    }
    *(ushort8v*)(x1 + (size_t)(pos0+pp)*128 + ch0) = o;
  }
}

// ---------------- kCD: MFMA offset/mask + softmax + descriptor + vectorized sampling ----
#define RS 120
__global__ __launch_bounds__(256) void kCD_dcn(const ushort_t* __restrict__ x1,
    const ushort_t* __restrict__ owmb, const float* __restrict__ obm,
    ushort_t* __restrict__ dcnout){
  __shared__ __align__(16) ushort_t xLb[16*YS];
  __shared__ float raw[16*RS];
  __shared__ __align__(16) float descW[576*4];
  __shared__ __align__(16) int   descO[576*4];
  int t = threadIdx.x;
  int pos0 = blockIdx.x*16;
  int n = pos0>>14, hw0 = pos0&16383, h = hw0>>7, w0 = hw0&127;
  const size_t imgbase = (size_t)n*16384*128;

  *(ushort8v*)(xLb + (t>>4)*YS + (t&15)*8) = *(const ushort8v*)(x1 + (size_t)pos0*128 + t*8);
  __syncthreads();

  // phase 2: MFMA linear, operand-swapped: D-row = weight-row, D-col = position
  {
    int wave = t>>6, lane = t&63;
    int ma = lane&15, quad = lane>>4;
    short8 afrag[4];
    #pragma unroll
    for (int ks=0; ks<4; ks++)
      afrag[ks] = *(const short8*)(xLb + ma*YS + ks*32 + quad*8);
    f32x4 acc[2];
    acc[0] = (f32x4){0.f,0.f,0.f,0.f};
    acc[1] = (f32x4){0.f,0.f,0.f,0.f};
    #pragma unroll
    for (int tile=0; tile<2; tile++){
      const ushort_t* brow = owmb + (size_t)(wave*32 + tile*16 + ma)*128 + quad*8;
      #pragma unroll
      for (int ks=0; ks<4; ks++){
        short8 bfrag = *(const short8*)(brow + ks*32);
        acc[tile] = __builtin_amdgcn_mfma_f32_16x16x32_bf16(bfrag, afrag[ks], acc[tile], 0,0,0);
      }
    }
    #pragma unroll
    for (int tile=0; tile<2; tile++){
      int row0 = wave*32 + tile*16 + quad*4;
      if (row0 < 112){
        f32x4 bias4 = *(const f32x4*)(obm + row0);
        f32x4 o;
        #pragma unroll
        for (int r=0;r<4;r++) o[r] = acc[tile][r] + bias4[r];
        *(f32x4*)(raw + ma*RS + row0) = o;
      }
    }
  }
  __syncthreads();

  if (t < 64){
    int p = t>>2, g = t&3;
    float* mr = raw + p*RS + 72 + g*9;
    float mx = -1e30f;
    for (int q=0;q<9;q++) mx = fmaxf(mx, mr[q]);
    float e[9]; float ssum=0.f;
    for (int q=0;q<9;q++){ e[q]=expf(mr[q]-mx); ssum+=e[q]; }
    float inv = 1.0f/ssum;
    for (int q=0;q<9;q++) mr[q] = e[q]*inv;
  }
  __syncthreads();

  for (int it=0; it<3; it++){
    int tid = t + 256*it;
    if (tid < 576){
      int pp = tid/36, rem = tid - pp*36;
      int g = rem/9, p = rem - g*9;
      int i = p/3, j = p - i*3;
      float ox = raw[pp*RS + 2*(g*9+p)];
      float oy = raw[pp*RS + 2*(g*9+p)+1];
      float mval = raw[pp*RS + 72 + g*9 + p];
      float px = (float)(w0 + pp + i - 1) + ox;
      float py = (float)(h + j - 1) + oy;
      float fx0 = floorf(px), fy0 = floorf(py);
      int ix0 = (int)fx0, iy0 = (int)fy0;
      float fx = px - fx0, fy = py - fy0;
      float vx0 = ((unsigned)ix0     < 128u) ? 1.f : 0.f;
      float vx1 = ((unsigned)(ix0+1) < 128u) ? 1.f : 0.f;
      float vy0 = ((unsigned)iy0     < 128u) ? 1.f : 0.f;
      float vy1 = ((unsigned)(iy0+1) < 128u) ? 1.f : 0.f;
      int cx0 = min(max(ix0,0),127), cx1 = min(max(ix0+1,0),127);
      int cy0 = min(max(iy0,0),127), cy1 = min(max(iy0+1,0),127);
      float4 wv;
      wv.x = (1.f-fx)*(1.f-fy)*mval*vx0*vy0;
      wv.y = fx*(1.f-fy)*mval*vx1*vy0;
      wv.z = (1.f-fx)*fy*mval*vx0*vy1;
      wv.w = fx*fy*mval*vx1*vy1;
      int4 ov;
      ov.x = (cy0*128+cx0)*128;
      ov.y = (cy0*128+cx1)*128;
      ov.z = (cy1*128+cx0)*128;
      ov.w = (cy1*128+cx1)*128;
      *(float4*)(descW + tid*4) = wv;
      *(int4*)(descO + tid*4) = ov;
    }
  }
  __syncthreads();

  {
    int pp = t>>4, l = t&15;
    int ch0 = l*8, g = l>>2;
    const ushort_t* ib = x1 + imgbase + ch0;
    float acc[8];
    #pragma unroll
    for (int j=0;j<8;j++) acc[j]=0.f;
    int dbase = pp*36 + g*9;
    #pragma unroll
    for (int p=0;p<9;p++){
      float4 wv = *(const float4*)(descW + (dbase+p)*4);
      int4  ov = *(const int4*)(descO + (dbase+p)*4);
      ushort8v v00 = *(const ushort8v*)(ib + ov.x);
      ushort8v v10 = *(const ushort8v*)(ib + ov.y);
      ushort8v v01 = *(const ushort8v*)(ib + ov.z);
      ushort8v v11 = *(const ushort8v*)(ib + ov.w);
      #pragma unroll
      for (int j=0;j<8;j++){
        float s = wv.x*b2f(v00[j]) + wv.y*b2f(v10[j]) + wv.z*b2f(v01[j]) + wv.w*b2f(v11[j]);
        acc[j] += s;
      }
    }
    ushort8v outv;
    #pragma unroll
    for (int j=0;j<8;j++) outv[j] = f2b(acc[j]);
    *(ushort8v*)(dcnout + (size_t)(pos0+pp)*128 + ch0) = outv;
  }
}

// ---------------- kE v4: MFMA outproj (hi+lo) + residual + fused LN2 stats + LN2-apply ----
// operand-swapped: D-row = out-channel, D-col = position. 32 pos/block.
// Writes BOTH raw x2 (residual for kFG) and normalized x2n (bf16, MFMA-ready A operand).
// x2n aliases dcnout (R0): all dcnout reads complete (data-dep into acc/epilogue) before
// the stats barrier; x2n writes happen after it; blocks touch disjoint position rows.
__global__ __launch_bounds__(256) void kE_outproj(const ushort_t* dcnout,
    const ushort_t* __restrict__ pwh, const ushort_t* __restrict__ pwl,
    const float* __restrict__ pb, const float* __restrict__ x,
    const float* __restrict__ n2w, const float* __restrict__ n2b,
    ushort_t* __restrict__ x2, ushort_t* x2n){
  __shared__ float partS[32*17], partQ[32*17];
  __shared__ float msh[32], rsh[32];
  int t = threadIdx.x;
  int pos0 = blockIdx.x*32;
  int n = pos0>>14, hw0 = pos0&16383;
  int wave = t>>6, lane = t&63;
  int ma = lane&15, quad = lane>>4;

  short8 af[2][4];
  #pragma unroll
  for (int mt=0; mt<2; mt++)
    #pragma unroll
    for (int ks=0; ks<4; ks++)
      af[mt][ks] = *(const short8*)(dcnout + (size_t)(pos0+mt*16+ma)*128 + ks*32 + quad*8);

  f32x4 acc[2][2];
  #pragma unroll
  for (int i=0;i<2;i++){ acc[i][0]=(f32x4){0.f,0.f,0.f,0.f}; acc[i][1]=(f32x4){0.f,0.f,0.f,0.f}; }
  #pragma unroll
  for (int tile=0; tile<2; tile++){
    int c0 = wave*32 + tile*16;
    const ushort_t* bh = pwh + (size_t)(c0 + ma)*128 + quad*8;
    const ushort_t* bl = pwl + (size_t)(c0 + ma)*128 + quad*8;
    #pragma unroll
    for (int ks=0; ks<4; ks++){
      short8 bfh = *(const short8*)(bh + ks*32);
      short8 bfl = *(const short8*)(bl + ks*32);
      #pragma unroll
      for (int mt=0; mt<2; mt++){
        acc[tile][mt] = __builtin_amdgcn_mfma_f32_16x16x32_bf16(bfh, af[mt][ks], acc[tile][mt], 0,0,0);
        acc[tile][mt] = __builtin_amdgcn_mfma_f32_16x16x32_bf16(bfl, af[mt][ks], acc[tile][mt], 0,0,0);
      }
    }
  }
  // epilogue: D[row=c][col=pos]; per (tile,mt): 4 consecutive channels at one position
  float vb[2][2][4];
  float sAcc[2], qAcc[2];
  sAcc[0]=0.f; sAcc[1]=0.f; qAcc[0]=0.f; qAcc[1]=0.f;
  #pragma unroll
  for (int tile=0; tile<2; tile++){
    int c0 = wave*32 + tile*16 + quad*4;
    f32x4 bias4 = *(const f32x4*)(pb + c0);
    #pragma unroll
    for (int mt=0; mt<2; mt++){
      int p = mt*16 + ma;
      ushort4v ov;
      #pragma unroll
      for (int r=0;r<4;r++){
        float res = x[((size_t)(n*128) + c0 + r)*HWsz + hw0 + p];
        float v = acc[tile][mt][r] + bias4[r] + res;
        ushort_t ub = f2b(v);
        ov[r] = ub;
        float vv = b2f(ub);
        vb[tile][mt][r] = vv;
        sAcc[mt] += vv; qAcc[mt] += vv*vv;
      }
      *(ushort4v*)(x2 + (size_t)(pos0+p)*128 + c0) = ov;
    }
  }
  #pragma unroll
  for (int mt=0; mt<2; mt++){
    int p = mt*16 + ma;
    partS[p*17 + wave*4 + quad] = sAcc[mt];
    partQ[p*17 + wave*4 + quad] = qAcc[mt];
  }
  __syncthreads();
  if (t < 32){
    float s=0.f, q=0.f;
    for (int i=0;i<16;i++){ s += partS[t*17+i]; q += partQ[t*17+i]; }
    float m = s*(1.0f/128.0f);
    float var = q*(1.0f/128.0f) - m*m;
    msh[t] = m; rsh[t] = rsqrtf(var+1e-6f);
  }
  __syncthreads();
  // LN2-apply: write normalized bf16 (same values kFG used to compute on-the-fly)
  #pragma unroll
  for (int tile=0; tile<2; tile++){
    int c0 = wave*32 + tile*16 + quad*4;
    f32x4 w4 = *(const f32x4*)(n2w + c0);
    f32x4 b4 = *(const f32x4*)(n2b + c0);
    #pragma unroll
    for (int mt=0; mt<2; mt++){
      int p = mt*16 + ma;
      float m = msh[p], r = rsh[p];
      ushort4v nv;
      #pragma unroll
      for (int rr=0;rr<4;rr++) nv[rr] = f2b((vb[tile][mt][rr]-m)*r*w4[rr] + b4[rr]);
      *(ushort4v*)(x2n + (size_t)(pos0+p)*128 + c0) = nv;
    }
  }
}

// ---------------- kFG v6: MFMA MLP on pre-normalized x2n ----------------
// Changes vs v5: (1) A-fragments are direct loads of x2n (LN2 moved into kE);
// (2) FC1 epilogue fused per-tile (live acc 64->8 regs, gelu overlaps next tile's MFMA);
// (3) fast tanh-GELU (~6 VALU ops vs ~35 for erff);
// (4) FC2 k-loop 1-deep software prefetch of hid (LDS) + w2b (global) fragments.
__global__ __launch_bounds__(256) void kFG_mfma(const ushort_t* __restrict__ x2n,
    const ushort_t* __restrict__ x2,
    const ushort_t* __restrict__ w1b, const float* __restrict__ b1,
    const ushort_t* __restrict__ w2b, const float* __restrict__ b2,
    float* __restrict__ out){
  __shared__ __align__(16) ushort_t hid[32*HS];
  int t = threadIdx.x;
  int pos0 = blockIdx.x*32;
  int n = pos0>>14, hw0 = pos0&16383;
  int wave = t>>6, lane = t&63;
  int ma = lane&15, quad = lane>>4;

  // A-fragments: direct bf16 loads (already normalized by kE)
  short8 af[2][4];
  #pragma unroll
  for (int ks=0; ks<4; ks++)
    #pragma unroll
    for (int mt=0; mt<2; mt++)
      af[mt][ks] = *(const short8*)(x2n + (size_t)(pos0+mt*16+ma)*128 + ks*32 + quad*8);

  // --- FC1: mfma(w1_frag, x_frag) -> D[row=n][col=pos], per-tile fused epilogue ---
  int nbase = wave*128;
  #pragma unroll
  for (int tile=0; tile<8; tile++){
    const ushort_t* brow = w1b + (size_t)(nbase + tile*16 + ma)*128 + quad*8;
    short8 bf[4];
    #pragma unroll
    for (int ks=0; ks<4; ks++) bf[ks] = *(const short8*)(brow + ks*32);
    f32x4 a0 = (f32x4){0.f,0.f,0.f,0.f};
    f32x4 a1 = (f32x4){0.f,0.f,0.f,0.f};
    #pragma unroll
    for (int ks=0; ks<4; ks++){
      a0 = __builtin_amdgcn_mfma_f32_16x16x32_bf16(bf[ks], af[0][ks], a0, 0,0,0);
      a1 = __builtin_amdgcn_mfma_f32_16x16x32_bf16(bf[ks], af[1][ks], a1, 0,0,0);
    }
    int n0 = nbase + tile*16 + quad*4;
    f32x4 bias4 = *(const f32x4*)(b1 + n0);
    ushort4v hv0, hv1;
    #pragma unroll
    for (int r=0;r<4;r++){
      hv0[r] = f2b(gelu_fast(a0[r] + bias4[r]));
      hv1[r] = f2b(gelu_fast(a1[r] + bias4[r]));
    }
    *(ushort4v*)(hid + ma*HS + n0) = hv0;       // p = ma
    *(ushort4v*)(hid + (16+ma)*HS + n0) = hv1;  // p = 16+ma
  }
  __syncthreads();

  // --- FC2: mfma(w2_frag, hid_frag) -> D[row=c][col=pos], 1-deep prefetch ---
  f32x4 acc2[2][2];
  acc2[0][0]=(f32x4){0.f,0.f,0.f,0.f}; acc2[0][1]=(f32x4){0.f,0.f,0.f,0.f};
  acc2[1][0]=(f32x4){0.f,0.f,0.f,0.f}; acc2[1][1]=(f32x4){0.f,0.f,0.f,0.f};
  const ushort_t* hb0 = hid + ma*HS + quad*8;
  const ushort_t* hb1 = hid + (16+ma)*HS + quad*8;
  const ushort_t* wb0 = w2b + (size_t)(wave*32 + ma)*512 + quad*8;
  const ushort_t* wb1 = w2b + (size_t)(wave*32 + 16 + ma)*512 + quad*8;
  short8 hf0 = *(const short8*)(hb0);
  short8 hf1 = *(const short8*)(hb1);
  short8 bf0 = *(const short8*)(wb0);
  short8 bf1 = *(const short8*)(wb1);
  for (int ks=0; ks<15; ks++){
    short8 nhf0 = *(const short8*)(hb0 + (ks+1)*32);
    short8 nhf1 = *(const short8*)(hb1 + (ks+1)*32);
    short8 nbf0 = *(const short8*)(wb0 + (ks+1)*32);
    short8 nbf1 = *(const short8*)(wb1 + (ks+1)*32);
    acc2[0][0] = __builtin_amdgcn_mfma_f32_16x16x32_bf16(bf0, hf0, acc2[0][0], 0,0,0);
    acc2[0][1] = __builtin_amdgcn_mfma_f32_16x16x32_bf16(bf0, hf1, acc2[0][1], 0,0,0);
    acc2[1][0] = __builtin_amdgcn_mfma_f32_16x16x32_bf16(bf1, hf0, acc2[1][0], 0,0,0);
    acc2[1][1] = __builtin_amdgcn_mfma_f32_16x16x32_bf16(bf1, hf1, acc2[1][1], 0,0,0);
    hf0=nhf0; hf1=nhf1; bf0=nbf0; bf1=nbf1;
  }
  acc2[0][0] = __builtin_amdgcn_mfma_f32_16x16x32_bf16(bf0, hf0, acc2[0][0], 0,0,0);
  acc2[0][1] = __builtin_amdgcn_mfma_f32_16x16x32_bf16(bf0, hf1, acc2[0][1], 0,0,0);
  acc2[1][0] = __builtin_amdgcn_mfma_f32_16x16x32_bf16(bf1, hf0, acc2[1][0], 0,0,0);
  acc2[1][1] = __builtin_amdgcn_mfma_f32_16x16x32_bf16(bf1, hf1, acc2[1][1], 0,0,0);

  // --- epilogue: + bias + residual (8B bf16 load), NCHW fp32 coalesced store ---
  #pragma unroll
  for (int tile=0; tile<2; tile++){
    int c0 = wave*32 + tile*16 + quad*4;
    f32x4 bias4 = *(const f32x4*)(b2 + c0);
    #pragma unroll
    for (int mt=0; mt<2; mt++){
      int p = mt*16 + ma;
      ushort4v rv = *(const ushort4v*)(x2 + (size_t)(pos0+p)*128 + c0);
      #pragma unroll
      for (int r=0;r<4;r++){
        float v = acc2[tile][mt][r] + bias4[r] + b2f(rv[r]);
        out[((size_t)(n*128) + c0 + r)*HWsz + hw0 + p] = v;
      }
    }
  }
}

extern "C" void kernel_launch(void* const* d_in, const int* in_sizes, int n_in,
                              void* d_out, int out_size, void* d_ws, size_t ws_size,
                              hipStream_t stream){
  const float* x     = (const float*)d_in[0];
  const float* n1w   = (const float*)d_in[1];
  const float* n1b   = (const float*)d_in[2];
  const float* dww   = (const float*)d_in[3];
  const float* dwb   = (const float*)d_in[4];
  const float* dwlnw = (const float*)d_in[5];
  const float* dwlnb = (const float*)d_in[6];
  const float* offw  = (const float*)d_in[7];
  const float* offb  = (const float*)d_in[8];
  const float* maskw = (const float*)d_in[9];
  const float* maskb = (const float*)d_in[10];
  const float* pw    = (const float*)d_in[11];
  const float* pb    = (const float*)d_in[12];
  const float* n2w   = (const float*)d_in[13];
  const float* n2b   = (const float*)d_in[14];
  const float* w1    = (const float*)d_in[15];
  const float* b1    = (const float*)d_in[16];
  const float* w2    = (const float*)d_in[17];
  const float* b2    = (const float*)d_in[18];

  // ws layout:
  //  R0 = ws[ 0,16MB): xcl (kA->kB) -> dcnout (kCD->kE) -> x2n (kE->kFG, in-place over dcnout)
  //  R1 = ws[16,32MB): x1  (kB->kCD) -> x2 (kE->kFG)
  //  +32MB: w1b(128K) w2b(128K) owmb(32K) pwh(32K) pwl(32K) bf16; dwwT+obm fp32
  char* wsb = (char*)d_ws;
  ushort_t* R0   = (ushort_t*)(wsb);
  ushort_t* R1   = (ushort_t*)(wsb + (16u<<20));
  ushort_t* w1b  = (ushort_t*)(wsb + (32u<<20));
  ushort_t* w2b  = (ushort_t*)(wsb + (32u<<20) + (128u<<10));
  ushort_t* owmb = (ushort_t*)(wsb + (32u<<20) + (256u<<10));
  ushort_t* pwh  = (ushort_t*)(wsb + (32u<<20) + (288u<<10));
  ushort_t* pwl  = (ushort_t*)(wsb + (32u<<20) + (320u<<10));
  float*    dwwT = (float*)(wsb + (32u<<20) + (352u<<10));
  float*    obm  = (float*)(wsb + (32u<<20) + (358u<<10));
  float* out = (float*)d_out;

  hipLaunchKernelGGL(kW_cvt,  dim3(256),   dim3(256), 0, stream, w1, w2, offw, maskw, dww, pw, offb, maskb, w1b, w2b, owmb, dwwT, pwh, pwl, obm);
  hipLaunchKernelGGL(kA_ln1,  dim3(1024),  dim3(256), 0, stream, x, n1w, n1b, R0);
  hipLaunchKernelGGL(kB_dw,   dim3(4096),  dim3(256), 0, stream, R0, dwwT, dwb, dwlnw, dwlnb, R1);
  hipLaunchKernelGGL(kCD_dcn, dim3(4096),  dim3(256), 0, stream, R1, owmb, obm, R0);
  hipLaunchKernelGGL(kE_outproj, dim3(2048), dim3(256), 0, stream, R0, pwh, pwl, pb, x, n2w, n2b, R1, R0);
  hipLaunchKernelGGL(kFG_mfma, dim3(2048), dim3(256), 0, stream, R0, R1, w1b, b1, w2b, b2, out);
}

// Round 2
// 276.918 us; speedup vs baseline: 1.1451x; 1.0789x over previous
//
#include <hip/hip_runtime.h>

typedef unsigned short ushort_t;
typedef short short8 __attribute__((ext_vector_type(8)));
typedef float f32x4 __attribute__((ext_vector_type(4)));
typedef ushort_t ushort8v __attribute__((ext_vector_type(8)));
typedef ushort_t ushort4v __attribute__((ext_vector_type(4)));

#define HWsz 16384
#define NHWsz 65536
// LDS strides (ushorts) for kA/kB/kCD padded tiles
#define YS 136

__device__ __forceinline__ float b2f(ushort_t u){ return __uint_as_float(((unsigned)u)<<16); }
__device__ __forceinline__ ushort_t f2b(float f){
  unsigned x = __float_as_uint(f);
  x += 0x7fffu + ((x>>16)&1u);
  return (ushort_t)(x>>16);
}
// tanh-form GELU: max |err| vs exact ~3e-4, below bf16 ulp at |x|~1+.
__device__ __forceinline__ float gelu_fast(float x){
  float t = x*x;
  float e = __expf(x*(1.5957691216f + 0.0713548163f*t));
  return x - x*__builtin_amdgcn_rcpf(1.0f + e);
}

// XOR-swizzled LDS byte offsets: row-bit into bank bits.
// 8 lanes per 4-bank group on b128 reads = minimum wave64 aliasing (free).
#define HSW(p, b) ((p)*1024 + ((b) ^ (((p)&7)<<4)))   // hid: 32 rows x 1024B
#define XSW(p, b) ((p)*256  + ((b) ^ (((p)&7)<<4)))   // xn : 32 rows x 256B

// ---------------- kW: weight preprocessing (once per launch) ----------------
__global__ __launch_bounds__(256) void kW_cvt(const float* __restrict__ w1, const float* __restrict__ w2,
    const float* __restrict__ offw, const float* __restrict__ maskw, const float* __restrict__ dww,
    const float* __restrict__ pw, const float* __restrict__ offb, const float* __restrict__ mb,
    ushort_t* __restrict__ w1b, ushort_t* __restrict__ w2b, ushort_t* __restrict__ owmb,
    float* __restrict__ dwwT, ushort_t* __restrict__ pwh, ushort_t* __restrict__ pwl,
    float* __restrict__ obm){
  int i = blockIdx.x*256 + threadIdx.x;   // 65536
  w1b[i] = f2b(w1[i]);
  w2b[i] = f2b(w2[i]);
  if (i < 16384){
    int row = i >> 7, k = i & 127;
    float v = 0.f;
    if (row < 72) v = offw[row*128 + k];
    else if (row < 108) v = maskw[(row-72)*128 + k];
    owmb[i] = f2b(v);
    float pv = pw[i];
    ushort_t hi = f2b(pv);
    pwh[i] = hi;
    pwl[i] = f2b(pv - b2f(hi));
  }
  if (i < 1152){
    int k = i >> 7, c = i & 127;
    dwwT[i] = dww[c*9 + k];
  }
  if (i < 128){
    obm[i] = (i < 72) ? offb[i] : ((i < 108) ? mb[i-72] : 0.f);
  }
}

// ---------------- kA: LN1, NCHW fp32 -> NHWC bf16 ----------------
__global__ __launch_bounds__(256) void kA_ln1(const float* __restrict__ x,
    const float* __restrict__ w, const float* __restrict__ b,
    ushort_t* __restrict__ xcl){
  __shared__ float tile[128*66];
  __shared__ float psum[256], psq[256];
  __shared__ float ms[64], rs[64];
  int t = threadIdx.x;
  int pos0 = blockIdx.x * 64;
  int n = pos0 >> 14, hw0 = pos0 & 16383;
  const float* xb = x + (size_t)n*128*HWsz + hw0;
  for (int i=0;i<32;i++){
    int e = i*256+t;
    int c = e>>6, p = e&63;
    tile[c*66+p] = xb[(size_t)c*HWsz + p];
  }
  __syncthreads();
  {
    int part = t>>6, p = t&63;
    float s=0.f, q=0.f;
    for (int c=part*32; c<part*32+32; c++){ float v = tile[c*66+p]; s+=v; q+=v*v; }
    psum[part*64+p]=s; psq[part*64+p]=q;
  }
  __syncthreads();
  if (t<64){
    float s=psum[t]+psum[64+t]+psum[128+t]+psum[192+t];
    float q=psq[t]+psq[64+t]+psq[128+t]+psq[192+t];
    float m = s*(1.0f/128.0f);
    float v = q*(1.0f/128.0f)-m*m;
    ms[t]=m; rs[t]=rsqrtf(v+1e-6f);
  }
  __syncthreads();
  for (int i=0;i<32;i++){
    int e = i*256+t;
    int p = e>>7, c = e&127;
    float v = (tile[c*66+p]-ms[p])*rs[p]*w[c]+b[c];
    xcl[(size_t)(pos0+p)*128 + c] = f2b(v);
  }
}

// ---------------- kB: depthwise 3x3 + bias + LN + GELU ----------------
__global__ __launch_bounds__(256) void kB_dw(const ushort_t* __restrict__ xcl,
    const float* __restrict__ dwwT, const float* __restrict__ dwb,
    const float* __restrict__ lnw, const float* __restrict__ lnb,
    ushort_t* __restrict__ x1){
  __shared__ float partS[16*17], partQ[16*17];
  __shared__ float ms[16], rs[16];
  int t = threadIdx.x;
  int pos0 = blockIdx.x*16;
  int n = pos0>>14, hw0 = pos0&16383, h = hw0>>7, w0 = hw0&127;
  int pp = t>>4, l = t&15, ch0 = l*8;
  int w = w0 + pp;
  float acc[8];
  {
    float4 b0 = *(const float4*)(dwb + ch0);
    float4 b1 = *(const float4*)(dwb + ch0 + 4);
    acc[0]=b0.x; acc[1]=b0.y; acc[2]=b0.z; acc[3]=b0.w;
    acc[4]=b1.x; acc[5]=b1.y; acc[6]=b1.z; acc[7]=b1.w;
  }
  #pragma unroll
  for (int kh=0; kh<3; kh++){
    int hy = h + kh - 1;
    if ((unsigned)hy < 128u){
      #pragma unroll
      for (int kw=0; kw<3; kw++){
        int wx = w + kw - 1;
        if ((unsigned)wx < 128u){
          ushort8v xv = *(const ushort8v*)(xcl + ((size_t)(n*16384 + hy*128 + wx))*128 + ch0);
          const float* wr = dwwT + (kh*3+kw)*128 + ch0;
          float4 w0v = *(const float4*)(wr);
          float4 w1v = *(const float4*)(wr+4);
          acc[0] += b2f(xv[0])*w0v.x; acc[1] += b2f(xv[1])*w0v.y;
          acc[2] += b2f(xv[2])*w0v.z; acc[3] += b2f(xv[3])*w0v.w;
          acc[4] += b2f(xv[4])*w1v.x; acc[5] += b2f(xv[5])*w1v.y;
          acc[6] += b2f(xv[6])*w1v.z; acc[7] += b2f(xv[7])*w1v.w;
        }
      }
    }
  }
  {
    float s=0.f, q=0.f;
    #pragma unroll
    for (int j=0;j<8;j++){ s+=acc[j]; q+=acc[j]*acc[j]; }
    partS[pp*17+l]=s; partQ[pp*17+l]=q;
  }
  __syncthreads();
  if (t<16){
    float s=0.f, q=0.f;
    for (int i=0;i<16;i++){ s += partS[t*17+i]; q += partQ[t*17+i]; }
    float m = s*(1.0f/128.0f);
    float var = q*(1.0f/128.0f) - m*m;
    ms[t]=m; rs[t]=rsqrtf(var+1e-6f);
  }
  __syncthreads();
  {
    float m = ms[pp], r = rs[pp];
    float4 lw0 = *(const float4*)(lnw + ch0);
    float4 lw1 = *(const float4*)(lnw + ch0 + 4);
    float4 lb0 = *(const float4*)(lnb + ch0);
    float4 lb1 = *(const float4*)(lnb + ch0 + 4);
    float lw[8] = {lw0.x,lw0.y,lw0.z,lw0.w,lw1.x,lw1.y,lw1.z,lw1.w};
    float lb[8] = {lb0.x,lb0.y,lb0.z,lb0.w,lb1.x,lb1.y,lb1.z,lb1.w};
    ushort8v o;
    #pragma unroll
    for (int j=0;j<8;j++){
      float v = (acc[j]-m)*r*lw[j]+lb[j];
      o[j] = f2b(gelu_fast(v));
    }
    *(ushort8v*)(x1 + (size_t)(pos0+pp)*128 + ch0) = o;
  }
}

// ---------------- kCD: MFMA offset/mask + softmax + descriptor + vectorized sampling ----
#define RS 120
__global__ __launch_bounds__(256) void kCD_dcn(const ushort_t* __restrict__ x1,
    const ushort_t* __restrict__ owmb, const float* __restrict__ obm,
    ushort_t* __restrict__ dcnout){
  __shared__ __align__(16) ushort_t xLb[16*YS];
  __shared__ float raw[16*RS];
  __shared__ __align__(16) float descW[576*4];
  __shared__ __align__(16) int   descO[576*4];
  int t = threadIdx.x;
  int pos0 = blockIdx.x*16;
  int n = pos0>>14, hw0 = pos0&16383, h = hw0>>7, w0 = hw0&127;
  const size_t imgbase = (size_t)n*16384*128;

  *(ushort8v*)(xLb + (t>>4)*YS + (t&15)*8) = *(const ushort8v*)(x1 + (size_t)pos0*128 + t*8);
  __syncthreads();

  // phase 2: MFMA linear, operand-swapped: D-row = weight-row, D-col = position
  {
    int wave = t>>6, lane = t&63;
    int ma = lane&15, quad = lane>>4;
    short8 afrag[4];
    #pragma unroll
    for (int ks=0; ks<4; ks++)
      afrag[ks] = *(const short8*)(xLb + ma*YS + ks*32 + quad*8);
    f32x4 acc[2];
    acc[0] = (f32x4){0.f,0.f,0.f,0.f};
    acc[1] = (f32x4){0.f,0.f,0.f,0.f};
    #pragma unroll
    for (int tile=0; tile<2; tile++){
      const ushort_t* brow = owmb + (size_t)(wave*32 + tile*16 + ma)*128 + quad*8;
      #pragma unroll
      for (int ks=0; ks<4; ks++){
        short8 bfrag = *(const short8*)(brow + ks*32);
        acc[tile] = __builtin_amdgcn_mfma_f32_16x16x32_bf16(bfrag, afrag[ks], acc[tile], 0,0,0);
      }
    }
    #pragma unroll
    for (int tile=0; tile<2; tile++){
      int row0 = wave*32 + tile*16 + quad*4;
      if (row0 < 112){
        f32x4 bias4 = *(const f32x4*)(obm + row0);
        f32x4 o;
        #pragma unroll
        for (int r=0;r<4;r++) o[r] = acc[tile][r] + bias4[r];
        *(f32x4*)(raw + ma*RS + row0) = o;
      }
    }
  }
  __syncthreads();

  if (t < 64){
    int p = t>>2, g = t&3;
    float* mr = raw + p*RS + 72 + g*9;
    float mx = -1e30f;
    for (int q=0;q<9;q++) mx = fmaxf(mx, mr[q]);
    float e[9]; float ssum=0.f;
    for (int q=0;q<9;q++){ e[q]=expf(mr[q]-mx); ssum+=e[q]; }
    float inv = 1.0f/ssum;
    for (int q=0;q<9;q++) mr[q] = e[q]*inv;
  }
  __syncthreads();

  for (int it=0; it<3; it++){
    int tid = t + 256*it;
    if (tid < 576){
      int pp = tid/36, rem = tid - pp*36;
      int g = rem/9, p = rem - g*9;
      int i = p/3, j = p - i*3;
      float ox = raw[pp*RS + 2*(g*9+p)];
      float oy = raw[pp*RS + 2*(g*9+p)+1];
      float mval = raw[pp*RS + 72 + g*9 + p];
      float px = (float)(w0 + pp + i - 1) + ox;
      float py = (float)(h + j - 1) + oy;
      float fx0 = floorf(px), fy0 = floorf(py);
      int ix0 = (int)fx0, iy0 = (int)fy0;
      float fx = px - fx0, fy = py - fy0;
      float vx0 = ((unsigned)ix0     < 128u) ? 1.f : 0.f;
      float vx1 = ((unsigned)(ix0+1) < 128u) ? 1.f : 0.f;
      float vy0 = ((unsigned)iy0     < 128u) ? 1.f : 0.f;
      float vy1 = ((unsigned)(iy0+1) < 128u) ? 1.f : 0.f;
      int cx0 = min(max(ix0,0),127), cx1 = min(max(ix0+1,0),127);
      int cy0 = min(max(iy0,0),127), cy1 = min(max(iy0+1,0),127);
      float4 wv;
      wv.x = (1.f-fx)*(1.f-fy)*mval*vx0*vy0;
      wv.y = fx*(1.f-fy)*mval*vx1*vy0;
      wv.z = (1.f-fx)*fy*mval*vx0*vy1;
      wv.w = fx*fy*mval*vx1*vy1;
      int4 ov;
      ov.x = (cy0*128+cx0)*128;
      ov.y = (cy0*128+cx1)*128;
      ov.z = (cy1*128+cx0)*128;
      ov.w = (cy1*128+cx1)*128;
      *(float4*)(descW + tid*4) = wv;
      *(int4*)(descO + tid*4) = ov;
    }
  }
  __syncthreads();

  {
    int pp = t>>4, l = t&15;
    int ch0 = l*8, g = l>>2;
    const ushort_t* ib = x1 + imgbase + ch0;
    float acc[8];
    #pragma unroll
    for (int j=0;j<8;j++) acc[j]=0.f;
    int dbase = pp*36 + g*9;
    #pragma unroll
    for (int p=0;p<9;p++){
      float4 wv = *(const float4*)(descW + (dbase+p)*4);
      int4  ov = *(const int4*)(descO + (dbase+p)*4);
      ushort8v v00 = *(const ushort8v*)(ib + ov.x);
      ushort8v v10 = *(const ushort8v*)(ib + ov.y);
      ushort8v v01 = *(const ushort8v*)(ib + ov.z);
      ushort8v v11 = *(const ushort8v*)(ib + ov.w);
      #pragma unroll
      for (int j=0;j<8;j++){
        float s = wv.x*b2f(v00[j]) + wv.y*b2f(v10[j]) + wv.z*b2f(v01[j]) + wv.w*b2f(v11[j]);
        acc[j] += s;
      }
    }
    ushort8v outv;
    #pragma unroll
    for (int j=0;j<8;j++) outv[j] = f2b(acc[j]);
    *(ushort8v*)(dcnout + (size_t)(pos0+pp)*128 + ch0) = outv;
  }
}

// ---------------- kEFG: fused outproj + residual + LN2 + MLP + residual ----------------
// One block = 32 positions, everything block-local:
//  phase1: outproj MFMA (hi+lo) + bias + residual(x) -> vb regs (== old x2, bf16-rounded)
//  stats : LN2 mean/rstd via LDS partials (aliased onto hid region, used before hid)
//  LN    : normalized bf16 -> xn LDS (XOR-swizzled)   [x2n never hits global]
//  FC1   : mfma(w1, xn) + GELU -> hid LDS (XOR-swizzled), 1-deep weight prefetch
//  FC2   : mfma(w2, hid), 1-deep h/w prefetch; epilogue: +bias +vb residual -> out (NCHW fp32)
// LDS = 32768 (hid) + 8192 (xn) = 40960 B exactly -> 4 blocks/CU (16 waves).
__global__ __launch_bounds__(256, 4) void kEFG(const ushort_t* __restrict__ dcnout,
    const ushort_t* __restrict__ pwh, const ushort_t* __restrict__ pwl,
    const float* __restrict__ pb, const float* __restrict__ x,
    const float* __restrict__ n2w, const float* __restrict__ n2b,
    const ushort_t* __restrict__ w1b, const float* __restrict__ b1,
    const ushort_t* __restrict__ w2b, const float* __restrict__ b2,
    float* __restrict__ out){
  __shared__ __align__(16) char hidb[32*1024];   // 32 KB: FC1 out; early-aliased by LN stats
  __shared__ __align__(16) char xnb[32*256];     // 8 KB: normalized x2
  float* partS = (float*)hidb;                   // 32*17
  float* partQ = partS + 32*17;
  float* msh   = partQ + 32*17;                  // 32
  float* rsh   = msh + 32;                       // 32  (total 4608 B < 32 KB)

  int t = threadIdx.x;
  int pos0 = blockIdx.x*32;
  int n = pos0>>14, hw0 = pos0&16383;
  int wave = t>>6, lane = t&63;
  int ma = lane&15, quad = lane>>4;

  // ---- phase 1: outproj (hi+lo split weights) ----
  short8 af[2][4];
  #pragma unroll
  for (int mt=0; mt<2; mt++)
    #pragma unroll
    for (int ks=0; ks<4; ks++)
      af[mt][ks] = *(const short8*)(dcnout + (size_t)(pos0+mt*16+ma)*128 + ks*32 + quad*8);

  f32x4 acc[2][2];
  #pragma unroll
  for (int i=0;i<2;i++){ acc[i][0]=(f32x4){0.f,0.f,0.f,0.f}; acc[i][1]=(f32x4){0.f,0.f,0.f,0.f}; }
  #pragma unroll
  for (int tile=0; tile<2; tile++){
    int c0 = wave*32 + tile*16;
    const ushort_t* bh = pwh + (size_t)(c0 + ma)*128 + quad*8;
    const ushort_t* bl = pwl + (size_t)(c0 + ma)*128 + quad*8;
    #pragma unroll
    for (int ks=0; ks<4; ks++){
      short8 bfh = *(const short8*)(bh + ks*32);
      short8 bfl = *(const short8*)(bl + ks*32);
      #pragma unroll
      for (int mt=0; mt<2; mt++){
        acc[tile][mt] = __builtin_amdgcn_mfma_f32_16x16x32_bf16(bfh, af[mt][ks], acc[tile][mt], 0,0,0);
        acc[tile][mt] = __builtin_amdgcn_mfma_f32_16x16x32_bf16(bfl, af[mt][ks], acc[tile][mt], 0,0,0);
      }
    }
  }

  // ---- epilogue 1: +bias +residual(x); vb = bf16-rounded x2 values (stay in regs) ----
  float vb[2][2][4];
  float sAcc[2], qAcc[2];
  sAcc[0]=0.f; sAcc[1]=0.f; qAcc[0]=0.f; qAcc[1]=0.f;
  #pragma unroll
  for (int tile=0; tile<2; tile++){
    int c0 = wave*32 + tile*16 + quad*4;
    f32x4 bias4 = *(const f32x4*)(pb + c0);
    #pragma unroll
    for (int mt=0; mt<2; mt++){
      int p = mt*16 + ma;
      #pragma unroll
      for (int r=0;r<4;r++){
        float res = x[((size_t)(n*128) + c0 + r)*HWsz + hw0 + p];
        float v = acc[tile][mt][r] + bias4[r] + res;
        float vv = b2f(f2b(v));
        vb[tile][mt][r] = vv;
        sAcc[mt] += vv; qAcc[mt] += vv*vv;
      }
    }
  }
  #pragma unroll
  for (int mt=0; mt<2; mt++){
    int p = mt*16 + ma;
    partS[p*17 + wave*4 + quad] = sAcc[mt];
    partQ[p*17 + wave*4 + quad] = qAcc[mt];
  }
  __syncthreads();
  if (t < 32){
    float s=0.f, q=0.f;
    for (int i=0;i<16;i++){ s += partS[t*17+i]; q += partQ[t*17+i]; }
    float m = s*(1.0f/128.0f);
    float var = q*(1.0f/128.0f) - m*m;
    msh[t] = m; rsh[t] = rsqrtf(var+1e-6f);
  }
  __syncthreads();

  // ---- LN2 apply -> xn (LDS, swizzled) ----
  #pragma unroll
  for (int tile=0; tile<2; tile++){
    int c0 = wave*32 + tile*16 + quad*4;
    f32x4 w4 = *(const f32x4*)(n2w + c0);
    f32x4 b4 = *(const f32x4*)(n2b + c0);
    #pragma unroll
    for (int mt=0; mt<2; mt++){
      int p = mt*16 + ma;
      float m = msh[p], r = rsh[p];
      ushort4v nv;
      #pragma unroll
      for (int rr=0;rr<4;rr++) nv[rr] = f2b((vb[tile][mt][rr]-m)*r*w4[rr] + b4[rr]);
      *(ushort4v*)(xnb + XSW(p, c0*2)) = nv;
    }
  }
  __syncthreads();

  // ---- FC1: mfma(w1_frag, xn_frag) -> hid (LDS), 1-deep weight prefetch ----
  short8 axf[2][4];
  #pragma unroll
  for (int ks=0; ks<4; ks++)
    #pragma unroll
    for (int mt=0; mt<2; mt++)
      axf[mt][ks] = *(const short8*)(xnb + XSW(mt*16+ma, ks*64 + quad*16));

  int nbase = wave*128;
  short8 wcur[4], wnxt[4];
  {
    const ushort_t* brow = w1b + (size_t)(nbase + ma)*128 + quad*8;
    #pragma unroll
    for (int ks=0; ks<4; ks++) wcur[ks] = *(const short8*)(brow + ks*32);
  }
  #pragma unroll
  for (int tile=0; tile<8; tile++){
    if (tile < 7){
      const ushort_t* brow = w1b + (size_t)(nbase + (tile+1)*16 + ma)*128 + quad*8;
      #pragma unroll
      for (int ks=0; ks<4; ks++) wnxt[ks] = *(const short8*)(brow + ks*32);
    }
    f32x4 a0 = (f32x4){0.f,0.f,0.f,0.f};
    f32x4 a1 = (f32x4){0.f,0.f,0.f,0.f};
    #pragma unroll
    for (int ks=0; ks<4; ks++){
      a0 = __builtin_amdgcn_mfma_f32_16x16x32_bf16(wcur[ks], axf[0][ks], a0, 0,0,0);
      a1 = __builtin_amdgcn_mfma_f32_16x16x32_bf16(wcur[ks], axf[1][ks], a1, 0,0,0);
    }
    int n0 = nbase + tile*16 + quad*4;
    f32x4 bias4 = *(const f32x4*)(b1 + n0);
    ushort4v hv0, hv1;
    #pragma unroll
    for (int r=0;r<4;r++){
      hv0[r] = f2b(gelu_fast(a0[r] + bias4[r]));
      hv1[r] = f2b(gelu_fast(a1[r] + bias4[r]));
    }
    *(ushort4v*)(hidb + HSW(ma,    n0*2)) = hv0;   // p = ma
    *(ushort4v*)(hidb + HSW(16+ma, n0*2)) = hv1;   // p = 16+ma
    #pragma unroll
    for (int ks=0; ks<4; ks++) wcur[ks] = wnxt[ks];
  }
  __syncthreads();

  // ---- FC2: mfma(w2_frag, hid_frag), 1-deep prefetch of both LDS and global ----
  f32x4 acc2[2][2];
  acc2[0][0]=(f32x4){0.f,0.f,0.f,0.f}; acc2[0][1]=(f32x4){0.f,0.f,0.f,0.f};
  acc2[1][0]=(f32x4){0.f,0.f,0.f,0.f}; acc2[1][1]=(f32x4){0.f,0.f,0.f,0.f};
  const ushort_t* wb0 = w2b + (size_t)(wave*32 + ma)*512 + quad*8;
  const ushort_t* wb1 = w2b + (size_t)(wave*32 + 16 + ma)*512 + quad*8;
  short8 hc0 = *(const short8*)(hidb + HSW(ma,    quad*16));
  short8 hc1 = *(const short8*)(hidb + HSW(16+ma, quad*16));
  short8 wc0 = *(const short8*)(wb0);
  short8 wc1 = *(const short8*)(wb1);
  #pragma unroll
  for (int ks=0; ks<16; ks++){
    short8 hn0, hn1, wn0, wn1;
    if (ks < 15){
      hn0 = *(const short8*)(hidb + HSW(ma,    (ks+1)*64 + quad*16));
      hn1 = *(const short8*)(hidb + HSW(16+ma, (ks+1)*64 + quad*16));
      wn0 = *(const short8*)(wb0 + (ks+1)*32);
      wn1 = *(const short8*)(wb1 + (ks+1)*32);
    }
    acc2[0][0] = __builtin_amdgcn_mfma_f32_16x16x32_bf16(wc0, hc0, acc2[0][0], 0,0,0);
    acc2[0][1] = __builtin_amdgcn_mfma_f32_16x16x32_bf16(wc0, hc1, acc2[0][1], 0,0,0);
    acc2[1][0] = __builtin_amdgcn_mfma_f32_16x16x32_bf16(wc1, hc0, acc2[1][0], 0,0,0);
    acc2[1][1] = __builtin_amdgcn_mfma_f32_16x16x32_bf16(wc1, hc1, acc2[1][1], 0,0,0);
    if (ks < 15){ hc0=hn0; hc1=hn1; wc0=wn0; wc1=wn1; }
  }

  // ---- epilogue 2: +bias +residual(vb regs), NCHW fp32 coalesced store ----
  #pragma unroll
  for (int tile=0; tile<2; tile++){
    int c0 = wave*32 + tile*16 + quad*4;
    f32x4 bias4 = *(const f32x4*)(b2 + c0);
    #pragma unroll
    for (int mt=0; mt<2; mt++){
      int p = mt*16 + ma;
      #pragma unroll
      for (int r=0;r<4;r++){
        float v = acc2[tile][mt][r] + bias4[r] + vb[tile][mt][r];
        out[((size_t)(n*128) + c0 + r)*HWsz + hw0 + p] = v;
      }
    }
  }
}

extern "C" void kernel_launch(void* const* d_in, const int* in_sizes, int n_in,
                              void* d_out, int out_size, void* d_ws, size_t ws_size,
                              hipStream_t stream){
  const float* x     = (const float*)d_in[0];
  const float* n1w   = (const float*)d_in[1];
  const float* n1b   = (const float*)d_in[2];
  const float* dww   = (const float*)d_in[3];
  const float* dwb   = (const float*)d_in[4];
  const float* dwlnw = (const float*)d_in[5];
  const float* dwlnb = (const float*)d_in[6];
  const float* offw  = (const float*)d_in[7];
  const float* offb  = (const float*)d_in[8];
  const float* maskw = (const float*)d_in[9];
  const float* maskb = (const float*)d_in[10];
  const float* pw    = (const float*)d_in[11];
  const float* pb    = (const float*)d_in[12];
  const float* n2w   = (const float*)d_in[13];
  const float* n2b   = (const float*)d_in[14];
  const float* w1    = (const float*)d_in[15];
  const float* b1    = (const float*)d_in[16];
  const float* w2    = (const float*)d_in[17];
  const float* b2    = (const float*)d_in[18];

  // ws layout:
  //  R0 = ws[ 0,16MB): xcl (kA->kB) -> dcnout (kCD->kEFG)
  //  R1 = ws[16,32MB): x1  (kB->kCD)
  //  +32MB: w1b(128K) w2b(128K) owmb(32K) pwh(32K) pwl(32K) bf16; dwwT+obm fp32
  char* wsb = (char*)d_ws;
  ushort_t* R0   = (ushort_t*)(wsb);
  ushort_t* R1   = (ushort_t*)(wsb + (16u<<20));
  ushort_t* w1b  = (ushort_t*)(wsb + (32u<<20));
  ushort_t* w2b  = (ushort_t*)(wsb + (32u<<20) + (128u<<10));
  ushort_t* owmb = (ushort_t*)(wsb + (32u<<20) + (256u<<10));
  ushort_t* pwh  = (ushort_t*)(wsb + (32u<<20) + (288u<<10));
  ushort_t* pwl  = (ushort_t*)(wsb + (32u<<20) + (320u<<10));
  float*    dwwT = (float*)(wsb + (32u<<20) + (352u<<10));
  float*    obm  = (float*)(wsb + (32u<<20) + (358u<<10));
  float* out = (float*)d_out;

  hipLaunchKernelGGL(kW_cvt,  dim3(256),   dim3(256), 0, stream, w1, w2, offw, maskw, dww, pw, offb, maskb, w1b, w2b, owmb, dwwT, pwh, pwl, obm);
  hipLaunchKernelGGL(kA_ln1,  dim3(1024),  dim3(256), 0, stream, x, n1w, n1b, R0);
  hipLaunchKernelGGL(kB_dw,   dim3(4096),  dim3(256), 0, stream, R0, dwwT, dwb, dwlnw, dwlnb, R1);
  hipLaunchKernelGGL(kCD_dcn, dim3(4096),  dim3(256), 0, stream, R1, owmb, obm, R0);
  hipLaunchKernelGGL(kEFG,    dim3(2048),  dim3(256), 0, stream, R0, pwh, pwl, pb, x, n2w, n2b, w1b, b1, w2b, b2, out);
}